// Round 11
// baseline (212.525 us; speedup 1.0000x reference)
//
#include <hip/hip_runtime.h>

#define Tn   2048
#define Dn   1024
#define KDn  256
#define NHn  16
#define NKVn 4
#define Rn   4096   // B*T

typedef short bf16x8 __attribute__((ext_vector_type(8)));
typedef float f32x4  __attribute__((ext_vector_type(4)));
typedef const __attribute__((address_space(1))) unsigned* gas_p;
typedef __attribute__((address_space(3))) unsigned* las_p;

// ---- device-global intermediates; referenced ONLY from device code ---------
__device__ unsigned short g_q[(size_t)Rn * Dn];              // [b][t][h][d]
__device__ unsigned short g_k[(size_t)Rn * KDn];             // [b][t][kvh][d]
__device__ unsigned short g_vt[(size_t)2 * NKVn * 64 * Tn];  // [b][kvh][d][t]
__device__ unsigned short g_y[(size_t)Rn * Dn];              // [b][t][h][d]
__device__ unsigned short g_xb[(size_t)Rn * Dn];             // bf16 x
__device__ unsigned short g_wq[(size_t)Dn * Dn];
__device__ unsigned short g_wk[(size_t)KDn * Dn];
__device__ unsigned short g_wv[(size_t)KDn * Dn];
__device__ unsigned short g_wp[(size_t)Dn * Dn];
__device__ float g_tq[Rn * 8];
__device__ float g_tv[Rn * 8];

static __device__ __forceinline__ float bf2f(unsigned short u) {
    return __uint_as_float(((unsigned)u) << 16);
}
static __device__ __forceinline__ unsigned short f2bf(float f) {
    unsigned u = __float_as_uint(f);
    u += 0x7fffu + ((u >> 16) & 1u);   // round-to-nearest-even
    return (unsigned short)(u >> 16);
}
static __device__ __forceinline__ unsigned pk2bf(float a, float b) {
    return (unsigned)f2bf(a) | ((unsigned)f2bf(b) << 16);
}
// single-instruction packed bf16 convert (RNE), attn-internal use
static __device__ __forceinline__ unsigned cvtpk(float a, float b) {
    unsigned r;
    asm("v_cvt_pk_bf16_f32 %0, %1, %2" : "=v"(r) : "v"(a), "v"(b));
    return r;
}
static __device__ __forceinline__ float wave_sum(float s) {
    #pragma unroll
    for (int off = 32; off; off >>= 1) s += __shfl_xor(s, off);
    return s;
}

// ---- fused prep: weight cast (blocks 0..2559) + LoRA temporaries -----------
#define NQ4 (Dn * Dn / 4)
#define NK4 (KDn * Dn / 4)
#define CASTB ((NQ4 * 2 + NK4 * 2) / 256)   // 2560 blocks of cast work
__global__ __launch_bounds__(256)
void prep(const float* __restrict__ x,
          const float* __restrict__ Aq,
          const float* __restrict__ Av,
          const float* __restrict__ Wq, const float* __restrict__ Wk,
          const float* __restrict__ Wv, const float* __restrict__ Wp) {
    if (blockIdx.x < CASTB) {
        // ---- weight cast Wq|Wk|Wv|Wp -> bf16 ----
        int i = blockIdx.x * 256 + threadIdx.x;
        const float* src; unsigned short* dst; int o;
        if      (i < NQ4)                 { src = Wq; dst = g_wq; o = i; }
        else if (i < NQ4 + NK4)           { src = Wk; dst = g_wk; o = i - NQ4; }
        else if (i < NQ4 + 2 * NK4)       { src = Wv; dst = g_wv; o = i - NQ4 - NK4; }
        else                              { src = Wp; dst = g_wp; o = i - NQ4 - 2 * NK4; }
        float4 v = ((const float4*)src)[o];
        ((uint2*)dst)[o] = make_uint2(pk2bf(v.x, v.y), pk2bf(v.z, v.w));
        return;
    }
    // ---- LoRA temporaries tq/tv = x@A^T + fused x fp32->bf16 cast ----
    int tid = threadIdx.x, wave = tid >> 6, lane = tid & 63;
    int row = (blockIdx.x - CASTB) * 4 + wave;
    const float4* xr = (const float4*)(x + (size_t)row * Dn);
    uint2* xbo = (uint2*)g_xb + (size_t)row * (Dn / 4);
    float aq[8], av[8];
    #pragma unroll
    for (int r = 0; r < 8; r++) { aq[r] = 0.f; av[r] = 0.f; }
    for (int it = 0; it < Dn / 256; it++) {
        int j = it * 64 + lane;
        float4 xv = xr[j];
        xbo[j] = make_uint2(pk2bf(xv.x, xv.y), pk2bf(xv.z, xv.w));
        #pragma unroll
        for (int r = 0; r < 8; r++) {
            float4 a4 = ((const float4*)(Aq + (size_t)r * Dn))[j];
            aq[r] += xv.x * a4.x + xv.y * a4.y + xv.z * a4.z + xv.w * a4.w;
        }
        #pragma unroll
        for (int r = 0; r < 8; r++) {
            float4 a4 = ((const float4*)(Av + (size_t)r * Dn))[j];
            av[r] += xv.x * a4.x + xv.y * a4.y + xv.z * a4.z + xv.w * a4.w;
        }
    }
    #pragma unroll
    for (int r = 0; r < 8; r++) { aq[r] = wave_sum(aq[r]); av[r] = wave_sum(av[r]); }
    if (lane == 0) {
        #pragma unroll
        for (int r = 0; r < 8; r++) { g_tq[row * 8 + r] = aq[r]; g_tv[row * 8 + r] = av[r]; }
    }
}

// ---- MFMA GEMM, 128x128 tile (m93-structure), BK=64, gll double-buffer -----
// Round-11: tile widened 128x64 -> 128x128. 4 waves in 2x2 (wr,wc), each
// owning a 64x64 quadrant with acc[4][4]. 32 MFMA/wave between barriers
// (was 16); staging + ds_read per FLOP halved (MFMA:LDS 2:1). Blocks halve
// to 384/256 (grid%8==0 kept for the bijective XCD swizzle). LDS 64KB ->
// 2 blocks/CU (launch_bounds(256,2) caps VGPR at 128).
// Each wave's 64-col window = EXACTLY one head (wc*64 is head-aligned), so
// the RMSNorm/RoPE/LoRA/gain epilogues carry over with a wc*64 offset.
// Tiles never straddle weight boundaries (1024, 1280 are 128-aligned):
//   region 0: n0 in {0..896}      Wq -> +LoRA -> RMSNorm+RoPE+gain -> g_q
//   region 1: n0 in {1024,1152}   Wk ->          RMSNorm+RoPE       -> g_k
//   region 2: n0 in {1280,1408}   Wv (2 kvh/tile) -> +LoRA -> transpose -> g_vt
// MODE 1 = out: A=g_y, W=g_wp, C=Cout fp32.
template<int MODE>
__global__ __launch_bounds__(256, 2)
void gemm_bt(float* __restrict__ Cout, const float* __restrict__ BqL,
             const float* __restrict__ BvL, const float* __restrict__ qgain,
             int M, int K) {
    const unsigned short* A = (MODE == 0) ? g_xb : g_y;

    // ---- chunked XCD swizzle (bijective: gridDim.x*gridDim.y % 8 == 0) ----
    int gx = gridDim.x;
    int flat = blockIdx.y * gx + blockIdx.x;
    int cpx = (gx * gridDim.y) >> 3;
    int flat2 = (flat & 7) * cpx + (flat >> 3);
    int n0 = (flat2 % gx) * 128, m0 = (flat2 / gx) * 128;

    const unsigned short* W;
    int wroff, region;
    if (MODE == 0) {
        if (n0 < 1024)      { W = g_wq; wroff = n0;        region = 0; }
        else if (n0 < 1280) { W = g_wk; wroff = n0 - 1024; region = 1; }
        else                { W = g_wv; wroff = n0 - 1280; region = 2; }
    } else { W = g_wp; wroff = n0; region = 3; }

    // SM (shorts): [0..16383]     = As double buffer (2 x 128 x 64)
    //              [16384..32767] = Ws double buffer (2 x 128 x 64)
    // region-2 epilogue reuses SM[0..17407] as 128 x (stride 136) transpose
    __shared__ __align__(16) unsigned short SM[32768];
    int tid = threadIdx.x;
    int w = tid >> 6, lane = tid & 63;
    int wr = w >> 1, wc = w & 1;           // 2x2 wave grid
    int m_ = lane & 15, quad = lane >> 4;

    // gll lane mapping at BK=64 (128B rows, 8 rows per 1KB wave-instruction)
    int lrow = lane >> 3, lseg = (lane & 7) * 8;
    const unsigned short* agp[4];
    #pragma unroll
    for (int i = 0; i < 4; i++)
        agp[i] = A + (size_t)(m0 + w * 32 + i * 8 + lrow) * K + lseg;
    const unsigned short* wgp[4];
    #pragma unroll
    for (int i = 0; i < 4; i++)
        wgp[i] = W + (size_t)(wroff + w * 32 + i * 8 + lrow) * K + lseg;
    int alb[4], wlb[4];
    #pragma unroll
    for (int i = 0; i < 4; i++) alb[i] = (w * 32 + i * 8) * 64;
    #pragma unroll
    for (int i = 0; i < 4; i++) wlb[i] = 16384 + (w * 32 + i * 8) * 64;

    f32x4 acc[4][4];
    #pragma unroll
    for (int im = 0; im < 4; im++)
        #pragma unroll
        for (int in = 0; in < 4; in++) acc[im][in] = (f32x4){0.f, 0.f, 0.f, 0.f};

    // stage tile 0 into buffer 0
    #pragma unroll
    for (int i = 0; i < 4; i++)
        __builtin_amdgcn_global_load_lds((gas_p)agp[i], (las_p)&SM[alb[i]], 16, 0, 0);
    #pragma unroll
    for (int i = 0; i < 4; i++)
        __builtin_amdgcn_global_load_lds((gas_p)wgp[i], (las_p)&SM[wlb[i]], 16, 0, 0);

    int nk = K >> 6;   // K/64
    for (int kt = 0; kt < nk; kt++) {
        __syncthreads();
        int cur = kt & 1, nxt = cur ^ 1;
        if (kt + 1 < nk) {
            int ko = (kt + 1) * 64;
            #pragma unroll
            for (int i = 0; i < 4; i++)
                __builtin_amdgcn_global_load_lds((gas_p)(agp[i] + ko),
                    (las_p)&SM[nxt * 8192 + alb[i]], 16, 0, 0);
            #pragma unroll
            for (int i = 0; i < 4; i++)
                __builtin_amdgcn_global_load_lds((gas_p)(wgp[i] + ko),
                    (las_p)&SM[wlb[i] + nxt * 8192], 16, 0, 0);
        }
        __syncthreads();
        #pragma unroll
        for (int kk = 0; kk < 2; kk++) {
            bf16x8 bfr[4];
            #pragma unroll
            for (int in = 0; in < 4; in++)
                bfr[in] = *(const bf16x8*)&SM[16384 + cur * 8192 +
                                              (wc * 64 + in * 16 + m_) * 64 + kk * 32 + quad * 8];
            #pragma unroll
            for (int im = 0; im < 4; im++) {
                bf16x8 af = *(const bf16x8*)&SM[cur * 8192 +
                                                (wr * 64 + im * 16 + m_) * 64 + kk * 32 + quad * 8];
                #pragma unroll
                for (int in = 0; in < 4; in++)
                    acc[im][in] = __builtin_amdgcn_mfma_f32_16x16x32_bf16(af, bfr[in], acc[im][in], 0, 0, 0);
            }
        }
    }

    int colbase = n0 + wc * 64;            // wave's 64-col window (one head)

    if (MODE == 1) {
        #pragma unroll
        for (int im = 0; im < 4; im++)
            #pragma unroll
            for (int r = 0; r < 4; r++) {
                int row = m0 + wr * 64 + im * 16 + quad * 4 + r;
                #pragma unroll
                for (int in = 0; in < 4; in++)
                    Cout[(size_t)row * Dn + (colbase + in * 16 + m_)] = acc[im][in][r];
            }
        return;
    }

    if (region <= 1) {
        // ---- fused LoRA(q) + RMSNorm + partial RoPE + gain(q) ----
        float blc[4][8];
        if (region == 0) {
            #pragma unroll
            for (int in = 0; in < 4; in++) {
                const float* bp = BqL + (size_t)(colbase + in * 16 + m_) * 8;
                #pragma unroll
                for (int j = 0; j < 8; j++) blc[in][j] = bp[j];
            }
        }
        // 0.18033688 = (1/sqrt(64)) * log2(e): fold softmax scale into q so
        // attention computes p = exp2(q.k) with zero per-score multiplies.
        float ghead = (region == 0) ? qgain[colbase >> 6] * 0.18033688011112042f : 1.0f;
        #pragma unroll
        for (int im = 0; im < 4; im++) {
            #pragma unroll
            for (int r = 0; r < 4; r++) {
                int row = m0 + wr * 64 + im * 16 + quad * 4 + r;
                float vv[4];
                float ss = 0.f;
                if (region == 0) {
                    const float* tp = g_tq + (size_t)row * 8;
                    float tv8[8];
                    #pragma unroll
                    for (int j = 0; j < 8; j++) tv8[j] = tp[j];
                    #pragma unroll
                    for (int in = 0; in < 4; in++) {
                        float val = acc[im][in][r];
                        #pragma unroll
                        for (int j = 0; j < 8; j++) val += tv8[j] * blc[in][j];
                        vv[in] = val; ss += val * val;
                    }
                } else {
                    #pragma unroll
                    for (int in = 0; in < 4; in++) { vv[in] = acc[im][in][r]; ss += vv[in] * vv[in]; }
                }
                ss += __shfl_xor(ss, 1); ss += __shfl_xor(ss, 2);
                ss += __shfl_xor(ss, 4); ss += __shfl_xor(ss, 8);
                float rs = rsqrtf(ss * (1.0f / 64.0f) + 1.1920929e-7f);
                #pragma unroll
                for (int in = 0; in < 4; in++) vv[in] *= rs;
                float p = __shfl_xor(vv[0], 8);
                int t = row & (Tn - 1);
                float fr = (float)t * exp2f(-(float)(m_ & 7) * 1.6609640474436813f);
                float c = cosf(fr), sn = sinf(fr);
                vv[0] = (m_ < 8) ? vv[0] * c + p * sn : p * sn - vv[0] * c;
                #pragma unroll
                for (int in = 0; in < 4; in++) {
                    float val = vv[in] * ghead;
                    int col = colbase + in * 16 + m_;
                    if (region == 0) g_q[(size_t)row * Dn + col] = f2bf(val);
                    else             g_k[(size_t)row * KDn + (col - 1024)] = f2bf(val);
                }
            }
        }
    } else {
        // ---- region 2: LoRA(v) + LDS transpose -> coalesced g_vt store ----
        // tile spans 2 kvh (128 cols); transpose buffer 128 x (stride 136)
        float blc[4][8];
        #pragma unroll
        for (int in = 0; in < 4; in++) {
            const float* bp = BvL + (size_t)(colbase - 1280 + in * 16 + m_) * 8;
            #pragma unroll
            for (int j = 0; j < 8; j++) blc[in][j] = bp[j];
        }
        __syncthreads();   // k-loop LDS now dead for all waves
        #pragma unroll
        for (int im = 0; im < 4; im++) {
            #pragma unroll
            for (int r = 0; r < 4; r++) {
                int rl = wr * 64 + im * 16 + quad * 4 + r;   // local t (0..127)
                const float* tp = g_tv + (size_t)(m0 + rl) * 8;
                float tv8[8];
                #pragma unroll
                for (int j = 0; j < 8; j++) tv8[j] = tp[j];
                #pragma unroll
                for (int in = 0; in < 4; in++) {
                    float val = acc[im][in][r];
                    #pragma unroll
                    for (int j = 0; j < 8; j++) val += tv8[j] * blc[in][j];
                    int lc = wc * 64 + in * 16 + m_;          // local col (0..127)
                    SM[lc * 136 + rl] = f2bf(val);            // [col][t], stride 136
                }
            }
        }
        __syncthreads();
        int bb = m0 >> 11, t0 = m0 & (Tn - 1);
        int kvh0 = (n0 - 1280) >> 6;
        int d = tid >> 2, tseg = (tid & 3) * 32;
        #pragma unroll
        for (int half = 0; half < 2; half++) {
            unsigned short* dst = g_vt +
                (((size_t)(bb * NKVn + kvh0 + half) * 64) + d) * Tn + t0 + tseg;
            const uint4* srcv = (const uint4*)&SM[(half * 64 + d) * 136 + tseg];
            uint4 c0 = srcv[0], c1 = srcv[1], c2 = srcv[2], c3 = srcv[3];
            ((uint4*)dst)[0] = c0; ((uint4*)dst)[1] = c1;
            ((uint4*)dst)[2] = c2; ((uint4*)dst)[3] = c3;
        }
    }
}

// -------- MFMA flash attention, 64-key tiles (round-4 verified, ~48us) ------
// Cooperative coalesced staging + one-tile-ahead register prefetch (rounds
// 5/6 proved direct-global fragment loads are latency-bound). Bank-group
// audit (r10): the 72-short stride already puts every LDS access at the b128
// floor — conflict counter level is inherent, not a lever.
__global__ __launch_bounds__(256, 4)
void attn_kernel() {
    __shared__ __align__(16) unsigned short KS[64 * 72];
    __shared__ __align__(16) unsigned short VS[64 * 72];
    __shared__ __align__(16) unsigned short Pt[4][16 * 72];
    int tid = threadIdx.x;
    int w = tid >> 6, lane = tid & 63;
    int q_ = lane & 15, quad = lane >> 4;
    int b = blockIdx.z, kvh = blockIdx.y, h = kvh * 4 + w;
    int bx = blockIdx.x;
    if ((kvh >> 1) & 1) bx = 127 - bx;      // balance work across co-resident blocks
    int qb = bx * 16;
    int qg = qb + q_;

    const unsigned short* qrow =
        g_q + ((size_t)(b * Tn + qg) * NHn + h) * 64 + quad * 8;
    bf16x8 Qf0 = *(const bf16x8*)qrow;
    bf16x8 Qf1 = *(const bf16x8*)(qrow + 32);

    int srow = tid >> 2, sseg = (tid & 3) * 16;
    const unsigned short* kgp =
        g_k + ((size_t)(b * Tn + srow) * NKVn + kvh) * 64 + sseg;
    const unsigned short* vgp =
        g_vt + ((size_t)(b * NKVn + kvh) * 64 + srow) * Tn + sseg;

    f32x4 accO[4];
    #pragma unroll
    for (int i = 0; i < 4; i++) accO[i] = (f32x4){0.f, 0.f, 0.f, 0.f};
    float lsum = 0.f;
    int ntiles = (qb + 79) >> 6;

    {   // stage tile 0
        uint4 ka = *(const uint4*)kgp, kb = *(const uint4*)(kgp + 8);
        uint4 va = *(const uint4*)vgp, vb = *(const uint4*)(vgp + 8);
        *(uint4*)&KS[srow * 72 + sseg] = ka;
        *(uint4*)&KS[srow * 72 + sseg + 8] = kb;
        *(uint4*)&VS[srow * 72 + sseg] = va;
        *(uint4*)&VS[srow * 72 + sseg + 8] = vb;
    }
    __syncthreads();

    for (int kt = 0; kt < ntiles; kt++) {
        bool pre = (kt + 1 < ntiles);
        uint4 kan, kbn, van, vbn;
        if (pre) {   // register prefetch of next tile; lands under the compute
            const unsigned short* kp = kgp + (size_t)(kt + 1) * (64 * NKVn * 64);
            const unsigned short* vp = vgp + (kt + 1) * 64;
            kan = *(const uint4*)kp; kbn = *(const uint4*)(kp + 8);
            van = *(const uint4*)vp; vbn = *(const uint4*)(vp + 8);
        }

        f32x4 s[4];
        __builtin_amdgcn_s_setprio(1);
        #pragma unroll
        for (int ss = 0; ss < 4; ss++) {
            bf16x8 ka = *(const bf16x8*)&KS[(ss * 16 + q_) * 72 + quad * 8];
            bf16x8 kb = *(const bf16x8*)&KS[(ss * 16 + q_) * 72 + 32 + quad * 8];
            s[ss] = (f32x4){0.f, 0.f, 0.f, 0.f};
            s[ss] = __builtin_amdgcn_mfma_f32_16x16x32_bf16(ka, Qf0, s[ss], 0, 0, 0);
            s[ss] = __builtin_amdgcn_mfma_f32_16x16x32_bf16(kb, Qf1, s[ss], 0, 0, 0);
        }
        __builtin_amdgcn_s_setprio(0);

        if (kt == ntiles - 1) {
            #pragma unroll
            for (int ss = 0; ss < 4; ss++) {
                int k0 = kt * 64 + ss * 16 + quad * 4;
                #pragma unroll
                for (int r = 0; r < 4; r++)
                    if (k0 + r > qg) s[ss][r] = -1e30f;
            }
        }
        float p[4][4];
        #pragma unroll
        for (int ss = 0; ss < 4; ss++)
            #pragma unroll
            for (int r = 0; r < 4; r++) {
                p[ss][r] = exp2f(s[ss][r]);   // scale pre-folded into q
                lsum += p[ss][r];
            }

        unsigned short* pb = &Pt[w][0];
        #pragma unroll
        for (int ss = 0; ss < 4; ss++)
            *(uint2*)&pb[q_ * 72 + ss * 16 + quad * 4] =
                make_uint2(cvtpk(p[ss][0], p[ss][1]), cvtpk(p[ss][2], p[ss][3]));
        bf16x8 pf0 = *(const bf16x8*)&pb[q_ * 72 + quad * 8];
        bf16x8 pf1 = *(const bf16x8*)&pb[q_ * 72 + 32 + quad * 8];

        __builtin_amdgcn_s_setprio(1);
        #pragma unroll
        for (int c = 0; c < 4; c++) {
            bf16x8 vf0 = *(const bf16x8*)&VS[(c * 16 + q_) * 72 + quad * 8];
            bf16x8 vf1 = *(const bf16x8*)&VS[(c * 16 + q_) * 72 + 32 + quad * 8];
            accO[c] = __builtin_amdgcn_mfma_f32_16x16x32_bf16(vf0, pf0, accO[c], 0, 0, 0);
            accO[c] = __builtin_amdgcn_mfma_f32_16x16x32_bf16(vf1, pf1, accO[c], 0, 0, 0);
        }
        __builtin_amdgcn_s_setprio(0);

        __syncthreads();               // all reads of KS/VS for this tile done
        if (pre) {
            *(uint4*)&KS[srow * 72 + sseg] = kan;
            *(uint4*)&KS[srow * 72 + sseg + 8] = kbn;
            *(uint4*)&VS[srow * 72 + sseg] = van;
            *(uint4*)&VS[srow * 72 + sseg + 8] = vbn;
        }
        __syncthreads();               // next tile staged
    }

    lsum += __shfl_xor(lsum, 16);
    lsum += __shfl_xor(lsum, 32);
    float invl = 1.0f / lsum;
    unsigned short* yp = g_y + ((size_t)(b * Tn + qg) * NHn + h) * 64;
    #pragma unroll
    for (int c = 0; c < 4; c++) {
        uint2 o = make_uint2(cvtpk(accO[c][0] * invl, accO[c][1] * invl),
                             cvtpk(accO[c][2] * invl, accO[c][3] * invl));
        *(uint2*)&yp[c * 16 + quad * 4] = o;
    }
}

// ----------------------------------------------------------------------------
extern "C" void kernel_launch(void* const* d_in, const int* in_sizes, int n_in,
                              void* d_out, int out_size, void* d_ws, size_t ws_size,
                              hipStream_t stream) {
    const float* x  = (const float*)d_in[0];
    const float* Wq = (const float*)d_in[1];
    const float* Wk = (const float*)d_in[2];
    const float* Wv = (const float*)d_in[3];
    const float* Wp = (const float*)d_in[4];
    const float* qg = (const float*)d_in[5];
    const float* Aq = (const float*)d_in[6];
    const float* Bq = (const float*)d_in[7];
    const float* Av = (const float*)d_in[8];
    const float* Bv = (const float*)d_in[9];
    float* out = (float*)d_out;

    prep<<<dim3(CASTB + Rn / 4), dim3(256), 0, stream>>>(x, Aq, Av, Wq, Wk, Wv, Wp);
    gemm_bt<0><<<dim3(1536 / 128, Rn / 128), dim3(256), 0, stream>>>(
        nullptr, Bq, Bv, qg, Rn, Dn);
    attn_kernel<<<dim3(Tn / 16, NKVn, 2), dim3(256), 0, stream>>>();
    gemm_bt<1><<<dim3(Dn / 128, Rn / 128), dim3(256), 0, stream>>>(
        out, nullptr, nullptr, nullptr, Rn, Dn);
}

// Round 12
// 210.656 us; speedup vs baseline: 1.0089x; 1.0089x over previous
//
#include <hip/hip_runtime.h>

#define Tn   2048
#define Dn   1024
#define KDn  256
#define NHn  16
#define NKVn 4
#define Rn   4096   // B*T

typedef short bf16x8 __attribute__((ext_vector_type(8)));
typedef float f32x4  __attribute__((ext_vector_type(4)));
typedef const __attribute__((address_space(1))) unsigned* gas_p;
typedef __attribute__((address_space(3))) unsigned* las_p;

// ---- device-global intermediates; referenced ONLY from device code ---------
__device__ unsigned short g_q[(size_t)Rn * Dn];              // [b][t][h][d]
__device__ unsigned short g_k[(size_t)Rn * KDn];             // [b][t][kvh][d]
__device__ unsigned short g_vt[(size_t)2 * NKVn * 64 * Tn];  // [b][kvh][d][t]
__device__ unsigned short g_y[(size_t)Rn * Dn];              // [b][t][h][d]
__device__ unsigned short g_xb[(size_t)Rn * Dn];             // bf16 x
__device__ unsigned short g_wq[(size_t)Dn * Dn];
__device__ unsigned short g_wk[(size_t)KDn * Dn];
__device__ unsigned short g_wv[(size_t)KDn * Dn];
__device__ unsigned short g_wp[(size_t)Dn * Dn];
__device__ float g_tq[Rn * 8];
__device__ float g_tv[Rn * 8];

static __device__ __forceinline__ float bf2f(unsigned short u) {
    return __uint_as_float(((unsigned)u) << 16);
}
static __device__ __forceinline__ unsigned short f2bf(float f) {
    unsigned u = __float_as_uint(f);
    u += 0x7fffu + ((u >> 16) & 1u);   // round-to-nearest-even
    return (unsigned short)(u >> 16);
}
static __device__ __forceinline__ unsigned pk2bf(float a, float b) {
    return (unsigned)f2bf(a) | ((unsigned)f2bf(b) << 16);
}
// single-instruction packed bf16 convert (RNE), attn-internal use
static __device__ __forceinline__ unsigned cvtpk(float a, float b) {
    unsigned r;
    asm("v_cvt_pk_bf16_f32 %0, %1, %2" : "=v"(r) : "v"(a), "v"(b));
    return r;
}
static __device__ __forceinline__ float wave_sum(float s) {
    #pragma unroll
    for (int off = 32; off; off >>= 1) s += __shfl_xor(s, off);
    return s;
}

// ---- fused prep: weight cast (blocks 0..2559) + LoRA temporaries -----------
#define NQ4 (Dn * Dn / 4)
#define NK4 (KDn * Dn / 4)
#define CASTB ((NQ4 * 2 + NK4 * 2) / 256)   // 2560 blocks of cast work
__global__ __launch_bounds__(256)
void prep(const float* __restrict__ x,
          const float* __restrict__ Aq,
          const float* __restrict__ Av,
          const float* __restrict__ Wq, const float* __restrict__ Wk,
          const float* __restrict__ Wv, const float* __restrict__ Wp) {
    if (blockIdx.x < CASTB) {
        // ---- weight cast Wq|Wk|Wv|Wp -> bf16 ----
        int i = blockIdx.x * 256 + threadIdx.x;
        const float* src; unsigned short* dst; int o;
        if      (i < NQ4)                 { src = Wq; dst = g_wq; o = i; }
        else if (i < NQ4 + NK4)           { src = Wk; dst = g_wk; o = i - NQ4; }
        else if (i < NQ4 + 2 * NK4)       { src = Wv; dst = g_wv; o = i - NQ4 - NK4; }
        else                              { src = Wp; dst = g_wp; o = i - NQ4 - 2 * NK4; }
        float4 v = ((const float4*)src)[o];
        ((uint2*)dst)[o] = make_uint2(pk2bf(v.x, v.y), pk2bf(v.z, v.w));
        return;
    }
    // ---- LoRA temporaries tq/tv = x@A^T + fused x fp32->bf16 cast ----
    int tid = threadIdx.x, wave = tid >> 6, lane = tid & 63;
    int row = (blockIdx.x - CASTB) * 4 + wave;
    const float4* xr = (const float4*)(x + (size_t)row * Dn);
    uint2* xbo = (uint2*)g_xb + (size_t)row * (Dn / 4);
    float aq[8], av[8];
    #pragma unroll
    for (int r = 0; r < 8; r++) { aq[r] = 0.f; av[r] = 0.f; }
    for (int it = 0; it < Dn / 256; it++) {
        int j = it * 64 + lane;
        float4 xv = xr[j];
        xbo[j] = make_uint2(pk2bf(xv.x, xv.y), pk2bf(xv.z, xv.w));
        #pragma unroll
        for (int r = 0; r < 8; r++) {
            float4 a4 = ((const float4*)(Aq + (size_t)r * Dn))[j];
            aq[r] += xv.x * a4.x + xv.y * a4.y + xv.z * a4.z + xv.w * a4.w;
        }
        #pragma unroll
        for (int r = 0; r < 8; r++) {
            float4 a4 = ((const float4*)(Av + (size_t)r * Dn))[j];
            av[r] += xv.x * a4.x + xv.y * a4.y + xv.z * a4.z + xv.w * a4.w;
        }
    }
    #pragma unroll
    for (int r = 0; r < 8; r++) { aq[r] = wave_sum(aq[r]); av[r] = wave_sum(av[r]); }
    if (lane == 0) {
        #pragma unroll
        for (int r = 0; r < 8; r++) { g_tq[row * 8 + r] = aq[r]; g_tv[row * 8 + r] = av[r]; }
    }
}

// ---- MFMA GEMM, 128x128 tile, BK=32 (m97 structure), gll double-buffer -----
// Round-12: round-11's regression dissected into (a) an accidental EXTRA
// __syncthreads after load-issue (drained the just-issued prefetch -> full
// serialization, MfmaUtil 5.9%) and (b) BK=64's 64KB LDS capping 2 blocks/CU.
// This version is the exact verified m97 shape: 128x128 tile, BK=32,
// SINGLE top-of-loop barrier (its vmcnt(0) drain covers the PREVIOUS
// iteration's loads — prefetch overlaps compute, round-4/10-verified
// semantics), 34.8KB LDS -> 4 blocks/CU, 16 MFMA per wave per K-step,
// MFMA:ds_read = 2:1. Round-11's FETCH_SIZE (37->17MB) confirmed the
// 128-wide tile's reuse gain; round-11's head-aligned epilogues (which
// PASSED the harness) are reused verbatim.
//   region 0: n0 in {0..896}      Wq -> +LoRA -> RMSNorm+RoPE+gain -> g_q
//   region 1: n0 in {1024,1152}   Wk ->          RMSNorm+RoPE       -> g_k
//   region 2: n0 in {1280,1408}   Wv (2 kvh/tile) -> +LoRA -> transpose -> g_vt
// MODE 1 = out: A=g_y, W=g_wp, C=Cout fp32.
template<int MODE>
__global__ __launch_bounds__(256, 2)
void gemm_bt(float* __restrict__ Cout, const float* __restrict__ BqL,
             const float* __restrict__ BvL, const float* __restrict__ qgain,
             int M, int K) {
    const unsigned short* A = (MODE == 0) ? g_xb : g_y;

    // ---- chunked XCD swizzle (bijective: gridDim.x*gridDim.y % 8 == 0) ----
    int gx = gridDim.x;
    int flat = blockIdx.y * gx + blockIdx.x;
    int cpx = (gx * gridDim.y) >> 3;
    int flat2 = (flat & 7) * cpx + (flat >> 3);
    int n0 = (flat2 % gx) * 128, m0 = (flat2 / gx) * 128;

    const unsigned short* W;
    int wroff, region;
    if (MODE == 0) {
        if (n0 < 1024)      { W = g_wq; wroff = n0;        region = 0; }
        else if (n0 < 1280) { W = g_wk; wroff = n0 - 1024; region = 1; }
        else                { W = g_wv; wroff = n0 - 1280; region = 2; }
    } else { W = g_wp; wroff = n0; region = 3; }

    // SM (shorts): [0..8191]     = As double buffer (2 x 128 x 32)
    //              [8192..16383] = Ws double buffer (2 x 128 x 32)
    // region-2 epilogue reuses SM[0..17407] as 128 x (stride 136) transpose
    __shared__ __align__(16) unsigned short SM[17408];
    int tid = threadIdx.x;
    int w = tid >> 6, lane = tid & 63;
    int wr = w >> 1, wc = w & 1;           // 2x2 wave grid
    int m_ = lane & 15, quad = lane >> 4;

    // gll lane mapping at BK=32 (64B rows, 16 rows per 1KB wave-instruction)
    int lrow = lane >> 2, lseg = (lane & 3) * 8;
    const unsigned short* agp[2];
    #pragma unroll
    for (int i = 0; i < 2; i++)
        agp[i] = A + (size_t)(m0 + w * 32 + i * 16 + lrow) * K + lseg;
    const unsigned short* wgp[2];
    #pragma unroll
    for (int i = 0; i < 2; i++)
        wgp[i] = W + (size_t)(wroff + w * 32 + i * 16 + lrow) * K + lseg;
    int alb[2], wlb[2];
    #pragma unroll
    for (int i = 0; i < 2; i++) alb[i] = (w * 32 + i * 16) * 32;
    #pragma unroll
    for (int i = 0; i < 2; i++) wlb[i] = 8192 + (w * 32 + i * 16) * 32;

    f32x4 acc[4][4];
    #pragma unroll
    for (int im = 0; im < 4; im++)
        #pragma unroll
        for (int in = 0; in < 4; in++) acc[im][in] = (f32x4){0.f, 0.f, 0.f, 0.f};

    // stage tile 0 into buffer 0
    #pragma unroll
    for (int i = 0; i < 2; i++)
        __builtin_amdgcn_global_load_lds((gas_p)agp[i], (las_p)&SM[alb[i]], 16, 0, 0);
    #pragma unroll
    for (int i = 0; i < 2; i++)
        __builtin_amdgcn_global_load_lds((gas_p)wgp[i], (las_p)&SM[wlb[i]], 16, 0, 0);

    int nk = K >> 5;   // K/32
    for (int kt = 0; kt < nk; kt++) {
        __syncthreads();   // drains prev iteration's loads (tile kt now in LDS)
        int cur = kt & 1, nxt = cur ^ 1;
        if (kt + 1 < nk) {
            int ko = (kt + 1) * 32;
            #pragma unroll
            for (int i = 0; i < 2; i++)
                __builtin_amdgcn_global_load_lds((gas_p)(agp[i] + ko),
                    (las_p)&SM[nxt * 4096 + alb[i]], 16, 0, 0);
            #pragma unroll
            for (int i = 0; i < 2; i++)
                __builtin_amdgcn_global_load_lds((gas_p)(wgp[i] + ko),
                    (las_p)&SM[wlb[i] + nxt * 4096], 16, 0, 0);
        }
        bf16x8 bfr[4];
        #pragma unroll
        for (int in = 0; in < 4; in++)
            bfr[in] = *(const bf16x8*)&SM[8192 + cur * 4096 +
                                          (wc * 64 + in * 16 + m_) * 32 + quad * 8];
        #pragma unroll
        for (int im = 0; im < 4; im++) {
            bf16x8 af = *(const bf16x8*)&SM[cur * 4096 +
                                            (wr * 64 + im * 16 + m_) * 32 + quad * 8];
            #pragma unroll
            for (int in = 0; in < 4; in++)
                acc[im][in] = __builtin_amdgcn_mfma_f32_16x16x32_bf16(af, bfr[in], acc[im][in], 0, 0, 0);
        }
    }

    int colbase = n0 + wc * 64;            // wave's 64-col window (one head)

    if (MODE == 1) {
        #pragma unroll
        for (int im = 0; im < 4; im++)
            #pragma unroll
            for (int r = 0; r < 4; r++) {
                int row = m0 + wr * 64 + im * 16 + quad * 4 + r;
                #pragma unroll
                for (int in = 0; in < 4; in++)
                    Cout[(size_t)row * Dn + (colbase + in * 16 + m_)] = acc[im][in][r];
            }
        return;
    }

    if (region <= 1) {
        // ---- fused LoRA(q) + RMSNorm + partial RoPE + gain(q) ----
        float blc[4][8];
        if (region == 0) {
            #pragma unroll
            for (int in = 0; in < 4; in++) {
                const float* bp = BqL + (size_t)(colbase + in * 16 + m_) * 8;
                #pragma unroll
                for (int j = 0; j < 8; j++) blc[in][j] = bp[j];
            }
        }
        // 0.18033688 = (1/sqrt(64)) * log2(e): fold softmax scale into q so
        // attention computes p = exp2(q.k) with zero per-score multiplies.
        float ghead = (region == 0) ? qgain[colbase >> 6] * 0.18033688011112042f : 1.0f;
        #pragma unroll
        for (int im = 0; im < 4; im++) {
            #pragma unroll
            for (int r = 0; r < 4; r++) {
                int row = m0 + wr * 64 + im * 16 + quad * 4 + r;
                float vv[4];
                float ss = 0.f;
                if (region == 0) {
                    const float* tp = g_tq + (size_t)row * 8;
                    float tv8[8];
                    #pragma unroll
                    for (int j = 0; j < 8; j++) tv8[j] = tp[j];
                    #pragma unroll
                    for (int in = 0; in < 4; in++) {
                        float val = acc[im][in][r];
                        #pragma unroll
                        for (int j = 0; j < 8; j++) val += tv8[j] * blc[in][j];
                        vv[in] = val; ss += val * val;
                    }
                } else {
                    #pragma unroll
                    for (int in = 0; in < 4; in++) { vv[in] = acc[im][in][r]; ss += vv[in] * vv[in]; }
                }
                ss += __shfl_xor(ss, 1); ss += __shfl_xor(ss, 2);
                ss += __shfl_xor(ss, 4); ss += __shfl_xor(ss, 8);
                float rs = rsqrtf(ss * (1.0f / 64.0f) + 1.1920929e-7f);
                #pragma unroll
                for (int in = 0; in < 4; in++) vv[in] *= rs;
                float p = __shfl_xor(vv[0], 8);
                int t = row & (Tn - 1);
                float fr = (float)t * exp2f(-(float)(m_ & 7) * 1.6609640474436813f);
                float c = cosf(fr), sn = sinf(fr);
                vv[0] = (m_ < 8) ? vv[0] * c + p * sn : p * sn - vv[0] * c;
                #pragma unroll
                for (int in = 0; in < 4; in++) {
                    float val = vv[in] * ghead;
                    int col = colbase + in * 16 + m_;
                    if (region == 0) g_q[(size_t)row * Dn + col] = f2bf(val);
                    else             g_k[(size_t)row * KDn + (col - 1024)] = f2bf(val);
                }
            }
        }
    } else {
        // ---- region 2: LoRA(v) + LDS transpose -> coalesced g_vt store ----
        // tile spans 2 kvh (128 cols); transpose buffer 128 x (stride 136)
        float blc[4][8];
        #pragma unroll
        for (int in = 0; in < 4; in++) {
            const float* bp = BvL + (size_t)(colbase - 1280 + in * 16 + m_) * 8;
            #pragma unroll
            for (int j = 0; j < 8; j++) blc[in][j] = bp[j];
        }
        __syncthreads();   // k-loop LDS now dead for all waves
        #pragma unroll
        for (int im = 0; im < 4; im++) {
            #pragma unroll
            for (int r = 0; r < 4; r++) {
                int rl = wr * 64 + im * 16 + quad * 4 + r;   // local t (0..127)
                const float* tp = g_tv + (size_t)(m0 + rl) * 8;
                float tv8[8];
                #pragma unroll
                for (int j = 0; j < 8; j++) tv8[j] = tp[j];
                #pragma unroll
                for (int in = 0; in < 4; in++) {
                    float val = acc[im][in][r];
                    #pragma unroll
                    for (int j = 0; j < 8; j++) val += tv8[j] * blc[in][j];
                    int lc = wc * 64 + in * 16 + m_;          // local col (0..127)
                    SM[lc * 136 + rl] = f2bf(val);            // [col][t], stride 136
                }
            }
        }
        __syncthreads();
        int bb = m0 >> 11, t0 = m0 & (Tn - 1);
        int kvh0 = (n0 - 1280) >> 6;
        int d = tid >> 2, tseg = (tid & 3) * 32;
        #pragma unroll
        for (int half = 0; half < 2; half++) {
            unsigned short* dst = g_vt +
                (((size_t)(bb * NKVn + kvh0 + half) * 64) + d) * Tn + t0 + tseg;
            const uint4* srcv = (const uint4*)&SM[(half * 64 + d) * 136 + tseg];
            uint4 c0 = srcv[0], c1 = srcv[1], c2 = srcv[2], c3 = srcv[3];
            ((uint4*)dst)[0] = c0; ((uint4*)dst)[1] = c1;
            ((uint4*)dst)[2] = c2; ((uint4*)dst)[3] = c3;
        }
    }
}

// -------- MFMA flash attention, 64-key tiles (round-4 verified, ~48us) ------
// Cooperative coalesced staging + one-tile-ahead register prefetch (rounds
// 5/6 proved direct-global fragment loads are latency-bound). Bank-group
// audit (r10): the 72-short stride already puts every LDS access at the b128
// floor — conflict counter level is inherent, not a lever.
__global__ __launch_bounds__(256, 4)
void attn_kernel() {
    __shared__ __align__(16) unsigned short KS[64 * 72];
    __shared__ __align__(16) unsigned short VS[64 * 72];
    __shared__ __align__(16) unsigned short Pt[4][16 * 72];
    int tid = threadIdx.x;
    int w = tid >> 6, lane = tid & 63;
    int q_ = lane & 15, quad = lane >> 4;
    int b = blockIdx.z, kvh = blockIdx.y, h = kvh * 4 + w;
    int bx = blockIdx.x;
    if ((kvh >> 1) & 1) bx = 127 - bx;      // balance work across co-resident blocks
    int qb = bx * 16;
    int qg = qb + q_;

    const unsigned short* qrow =
        g_q + ((size_t)(b * Tn + qg) * NHn + h) * 64 + quad * 8;
    bf16x8 Qf0 = *(const bf16x8*)qrow;
    bf16x8 Qf1 = *(const bf16x8*)(qrow + 32);

    int srow = tid >> 2, sseg = (tid & 3) * 16;
    const unsigned short* kgp =
        g_k + ((size_t)(b * Tn + srow) * NKVn + kvh) * 64 + sseg;
    const unsigned short* vgp =
        g_vt + ((size_t)(b * NKVn + kvh) * 64 + srow) * Tn + sseg;

    f32x4 accO[4];
    #pragma unroll
    for (int i = 0; i < 4; i++) accO[i] = (f32x4){0.f, 0.f, 0.f, 0.f};
    float lsum = 0.f;
    int ntiles = (qb + 79) >> 6;

    {   // stage tile 0
        uint4 ka = *(const uint4*)kgp, kb = *(const uint4*)(kgp + 8);
        uint4 va = *(const uint4*)vgp, vb = *(const uint4*)(vgp + 8);
        *(uint4*)&KS[srow * 72 + sseg] = ka;
        *(uint4*)&KS[srow * 72 + sseg + 8] = kb;
        *(uint4*)&VS[srow * 72 + sseg] = va;
        *(uint4*)&VS[srow * 72 + sseg + 8] = vb;
    }
    __syncthreads();

    for (int kt = 0; kt < ntiles; kt++) {
        bool pre = (kt + 1 < ntiles);
        uint4 kan, kbn, van, vbn;
        if (pre) {   // register prefetch of next tile; lands under the compute
            const unsigned short* kp = kgp + (size_t)(kt + 1) * (64 * NKVn * 64);
            const unsigned short* vp = vgp + (kt + 1) * 64;
            kan = *(const uint4*)kp; kbn = *(const uint4*)(kp + 8);
            van = *(const uint4*)vp; vbn = *(const uint4*)(vp + 8);
        }

        f32x4 s[4];
        __builtin_amdgcn_s_setprio(1);
        #pragma unroll
        for (int ss = 0; ss < 4; ss++) {
            bf16x8 ka = *(const bf16x8*)&KS[(ss * 16 + q_) * 72 + quad * 8];
            bf16x8 kb = *(const bf16x8*)&KS[(ss * 16 + q_) * 72 + 32 + quad * 8];
            s[ss] = (f32x4){0.f, 0.f, 0.f, 0.f};
            s[ss] = __builtin_amdgcn_mfma_f32_16x16x32_bf16(ka, Qf0, s[ss], 0, 0, 0);
            s[ss] = __builtin_amdgcn_mfma_f32_16x16x32_bf16(kb, Qf1, s[ss], 0, 0, 0);
        }
        __builtin_amdgcn_s_setprio(0);

        if (kt == ntiles - 1) {
            #pragma unroll
            for (int ss = 0; ss < 4; ss++) {
                int k0 = kt * 64 + ss * 16 + quad * 4;
                #pragma unroll
                for (int r = 0; r < 4; r++)
                    if (k0 + r > qg) s[ss][r] = -1e30f;
            }
        }
        float p[4][4];
        #pragma unroll
        for (int ss = 0; ss < 4; ss++)
            #pragma unroll
            for (int r = 0; r < 4; r++) {
                p[ss][r] = exp2f(s[ss][r]);   // scale pre-folded into q
                lsum += p[ss][r];
            }

        unsigned short* pb = &Pt[w][0];
        #pragma unroll
        for (int ss = 0; ss < 4; ss++)
            *(uint2*)&pb[q_ * 72 + ss * 16 + quad * 4] =
                make_uint2(cvtpk(p[ss][0], p[ss][1]), cvtpk(p[ss][2], p[ss][3]));
        bf16x8 pf0 = *(const bf16x8*)&pb[q_ * 72 + quad * 8];
        bf16x8 pf1 = *(const bf16x8*)&pb[q_ * 72 + 32 + quad * 8];

        __builtin_amdgcn_s_setprio(1);
        #pragma unroll
        for (int c = 0; c < 4; c++) {
            bf16x8 vf0 = *(const bf16x8*)&VS[(c * 16 + q_) * 72 + quad * 8];
            bf16x8 vf1 = *(const bf16x8*)&VS[(c * 16 + q_) * 72 + 32 + quad * 8];
            accO[c] = __builtin_amdgcn_mfma_f32_16x16x32_bf16(vf0, pf0, accO[c], 0, 0, 0);
            accO[c] = __builtin_amdgcn_mfma_f32_16x16x32_bf16(vf1, pf1, accO[c], 0, 0, 0);
        }
        __builtin_amdgcn_s_setprio(0);

        __syncthreads();               // all reads of KS/VS for this tile done
        if (pre) {
            *(uint4*)&KS[srow * 72 + sseg] = kan;
            *(uint4*)&KS[srow * 72 + sseg + 8] = kbn;
            *(uint4*)&VS[srow * 72 + sseg] = van;
            *(uint4*)&VS[srow * 72 + sseg + 8] = vbn;
        }
        __syncthreads();               // next tile staged
    }

    lsum += __shfl_xor(lsum, 16);
    lsum += __shfl_xor(lsum, 32);
    float invl = 1.0f / lsum;
    unsigned short* yp = g_y + ((size_t)(b * Tn + qg) * NHn + h) * 64;
    #pragma unroll
    for (int c = 0; c < 4; c++) {
        uint2 o = make_uint2(cvtpk(accO[c][0] * invl, accO[c][1] * invl),
                             cvtpk(accO[c][2] * invl, accO[c][3] * invl));
        *(uint2*)&yp[c * 16 + quad * 4] = o;
    }
}

// ----------------------------------------------------------------------------
extern "C" void kernel_launch(void* const* d_in, const int* in_sizes, int n_in,
                              void* d_out, int out_size, void* d_ws, size_t ws_size,
                              hipStream_t stream) {
    const float* x  = (const float*)d_in[0];
    const float* Wq = (const float*)d_in[1];
    const float* Wk = (const float*)d_in[2];
    const float* Wv = (const float*)d_in[3];
    const float* Wp = (const float*)d_in[4];
    const float* qg = (const float*)d_in[5];
    const float* Aq = (const float*)d_in[6];
    const float* Bq = (const float*)d_in[7];
    const float* Av = (const float*)d_in[8];
    const float* Bv = (const float*)d_in[9];
    float* out = (float*)d_out;

    prep<<<dim3(CASTB + Rn / 4), dim3(256), 0, stream>>>(x, Aq, Av, Wq, Wk, Wv, Wp);
    gemm_bt<0><<<dim3(1536 / 128, Rn / 128), dim3(256), 0, stream>>>(
        nullptr, Bq, Bv, qg, Rn, Dn);
    attn_kernel<<<dim3(Tn / 16, NKVn, 2), dim3(256), 0, stream>>>();
    gemm_bt<1><<<dim3(Dn / 128, Rn / 128), dim3(256), 0, stream>>>(
        out, nullptr, nullptr, nullptr, Rn, Dn);
}

// Round 13
// 187.081 us; speedup vs baseline: 1.1360x; 1.1260x over previous
//
#include <hip/hip_runtime.h>

#define Tn   2048
#define Dn   1024
#define KDn  256
#define NHn  16
#define NKVn 4
#define Rn   4096   // B*T

typedef short bf16x8 __attribute__((ext_vector_type(8)));
typedef float f32x4  __attribute__((ext_vector_type(4)));
typedef const __attribute__((address_space(1))) unsigned* gas_p;
typedef __attribute__((address_space(3))) unsigned* las_p;

// ---- device-global intermediates; referenced ONLY from device code ---------
__device__ unsigned short g_q[(size_t)Rn * Dn];              // [b][t][h][d]
__device__ unsigned short g_k[(size_t)Rn * KDn];             // [b][t][kvh][d]
__device__ unsigned short g_vt[(size_t)2 * NKVn * 64 * Tn];  // [b][kvh][d][t]
__device__ unsigned short g_y[(size_t)Rn * Dn];              // [b][t][h][d]
__device__ unsigned short g_xb[(size_t)Rn * Dn];             // bf16 x
__device__ unsigned short g_wq[(size_t)Dn * Dn];
__device__ unsigned short g_wk[(size_t)KDn * Dn];
__device__ unsigned short g_wv[(size_t)KDn * Dn];
__device__ unsigned short g_wp[(size_t)Dn * Dn];
__device__ float g_tq[Rn * 8];
__device__ float g_tv[Rn * 8];

static __device__ __forceinline__ float bf2f(unsigned short u) {
    return __uint_as_float(((unsigned)u) << 16);
}
static __device__ __forceinline__ unsigned short f2bf(float f) {
    unsigned u = __float_as_uint(f);
    u += 0x7fffu + ((u >> 16) & 1u);   // round-to-nearest-even
    return (unsigned short)(u >> 16);
}
static __device__ __forceinline__ unsigned pk2bf(float a, float b) {
    return (unsigned)f2bf(a) | ((unsigned)f2bf(b) << 16);
}
// single-instruction packed bf16 convert (RNE), attn-internal use
static __device__ __forceinline__ unsigned cvtpk(float a, float b) {
    unsigned r;
    asm("v_cvt_pk_bf16_f32 %0, %1, %2" : "=v"(r) : "v"(a), "v"(b));
    return r;
}
static __device__ __forceinline__ float wave_sum(float s) {
    #pragma unroll
    for (int off = 32; off; off >>= 1) s += __shfl_xor(s, off);
    return s;
}

// ---- fused prep: weight cast (blocks 0..2559) + LoRA temporaries -----------
// cast_w and lora_tmp merged into one launch (independent work; the pure-
// memory cast overlaps the VALU-heavy LoRA). Verified round 10.
#define NQ4 (Dn * Dn / 4)
#define NK4 (KDn * Dn / 4)
#define CASTB ((NQ4 * 2 + NK4 * 2) / 256)   // 2560 blocks of cast work
__global__ __launch_bounds__(256)
void prep(const float* __restrict__ x,
          const float* __restrict__ Aq,
          const float* __restrict__ Av,
          const float* __restrict__ Wq, const float* __restrict__ Wk,
          const float* __restrict__ Wv, const float* __restrict__ Wp) {
    if (blockIdx.x < CASTB) {
        // ---- weight cast Wq|Wk|Wv|Wp -> bf16 ----
        int i = blockIdx.x * 256 + threadIdx.x;
        const float* src; unsigned short* dst; int o;
        if      (i < NQ4)                 { src = Wq; dst = g_wq; o = i; }
        else if (i < NQ4 + NK4)           { src = Wk; dst = g_wk; o = i - NQ4; }
        else if (i < NQ4 + 2 * NK4)       { src = Wv; dst = g_wv; o = i - NQ4 - NK4; }
        else                              { src = Wp; dst = g_wp; o = i - NQ4 - 2 * NK4; }
        float4 v = ((const float4*)src)[o];
        ((uint2*)dst)[o] = make_uint2(pk2bf(v.x, v.y), pk2bf(v.z, v.w));
        return;
    }
    // ---- LoRA temporaries tq/tv = x@A^T + fused x fp32->bf16 cast ----
    int tid = threadIdx.x, wave = tid >> 6, lane = tid & 63;
    int row = (blockIdx.x - CASTB) * 4 + wave;
    const float4* xr = (const float4*)(x + (size_t)row * Dn);
    uint2* xbo = (uint2*)g_xb + (size_t)row * (Dn / 4);
    float aq[8], av[8];
    #pragma unroll
    for (int r = 0; r < 8; r++) { aq[r] = 0.f; av[r] = 0.f; }
    for (int it = 0; it < Dn / 256; it++) {
        int j = it * 64 + lane;
        float4 xv = xr[j];
        xbo[j] = make_uint2(pk2bf(xv.x, xv.y), pk2bf(xv.z, xv.w));
        #pragma unroll
        for (int r = 0; r < 8; r++) {
            float4 a4 = ((const float4*)(Aq + (size_t)r * Dn))[j];
            aq[r] += xv.x * a4.x + xv.y * a4.y + xv.z * a4.z + xv.w * a4.w;
        }
        #pragma unroll
        for (int r = 0; r < 8; r++) {
            float4 a4 = ((const float4*)(Av + (size_t)r * Dn))[j];
            av[r] += xv.x * a4.x + xv.y * a4.y + xv.z * a4.z + xv.w * a4.w;
        }
    }
    #pragma unroll
    for (int r = 0; r < 8; r++) { aq[r] = wave_sum(aq[r]); av[r] = wave_sum(av[r]); }
    if (lane == 0) {
        #pragma unroll
        for (int r = 0; r < 8; r++) { g_tq[row * 8 + r] = aq[r]; g_tv[row * 8 + r] = av[r]; }
    }
}

// ---- MFMA GEMM, 128x64 tile, BK=64, gll double-buffer ----------------------
// VERIFIED OPTIMUM (round 10, 189.6us end-to-end). Session A/B evidence for
// this exact shape:
//  * 128x64 tile beats 128x128 for THESE skinny GEMMs (N=1536/1024): grids
//    768/512 blocks = 3/2 per CU vs 384/256 = 1.5/1 — co-residency hides the
//    per-K-step barrier drain (m102 shape-curve mechanism; r11/r12 measured
//    128^2 variants at +23/+6us normalized).
//  * BK=64: 16 MFMA/wave between barriers, 16 K-steps (r1->r2: -25us).
//  * bijective chunked XCD swizzle (T1) for L2 panel locality.
//  * counted-vmcnt (T4) measured NEUTRAL here (r9, matching m131) — plain
//    __syncthreads kept (its vmcnt(0) drain covers the PREVIOUS iteration's
//    loads; prefetch issued after the barrier overlaps this tile's compute).
// MODE 0 = fused QKV over concatenated N=1536:
//   region 0 (cols 0..1023):    Wq -> +LoRA -> RMSNorm+RoPE+gain -> g_q
//     (gain pre-multiplied by 0.125*log2e so attn uses exp2(s) directly)
//   region 1 (cols 1024..1279): Wk ->          RMSNorm+RoPE       -> g_k
//   region 2 (cols 1280..1535): Wv -> +LoRA -> LDS transpose -> g_vt coalesced
// MODE 1 = out: A=g_y, W=g_wp, C=Cout fp32.
template<int MODE>
__global__ __launch_bounds__(256, 2)
void gemm_bt(float* __restrict__ Cout, const float* __restrict__ BqL,
             const float* __restrict__ BvL, const float* __restrict__ qgain,
             int M, int K) {
    const unsigned short* A = (MODE == 0) ? g_xb : g_y;

    // ---- chunked XCD swizzle (bijective: gridDim.x*gridDim.y % 8 == 0) ----
    int gx = gridDim.x;
    int flat = blockIdx.y * gx + blockIdx.x;
    int cpx = (gx * gridDim.y) >> 3;
    int flat2 = (flat & 7) * cpx + (flat >> 3);
    int n0 = (flat2 % gx) * 64, m0 = (flat2 / gx) * 128;

    const unsigned short* W;
    int wroff, region;
    if (MODE == 0) {
        if (n0 < 1024)      { W = g_wq; wroff = n0;        region = 0; }
        else if (n0 < 1280) { W = g_wk; wroff = n0 - 1024; region = 1; }
        else                { W = g_wv; wroff = n0 - 1280; region = 2; }
    } else { W = g_wp; wroff = n0; region = 3; }

    // SM (shorts): [0..16383]      = As double buffer (2 x 128 x 64)
    //              [16384..24575]  = Ws double buffer (2 x 64 x 64)
    // region-2 epilogue reuses SM[0..8703] as 64 x (stride 136) transpose buf
    __shared__ __align__(16) unsigned short SM[24576];
    int tid = threadIdx.x;
    int w = tid >> 6, lane = tid & 63;
    int m_ = lane & 15, quad = lane >> 4;

    // gll lane mapping at BK=64 (128B rows, 8 rows per 1KB wave-instruction)
    int lrow = lane >> 3, lseg = (lane & 7) * 8;
    const unsigned short* agp[4];
    #pragma unroll
    for (int i = 0; i < 4; i++)
        agp[i] = A + (size_t)(m0 + w * 32 + i * 8 + lrow) * K + lseg;
    const unsigned short* wgp[2];
    #pragma unroll
    for (int i = 0; i < 2; i++)
        wgp[i] = W + (size_t)(wroff + w * 16 + i * 8 + lrow) * K + lseg;
    int alb[4], wlb[2];
    #pragma unroll
    for (int i = 0; i < 4; i++) alb[i] = (w * 32 + i * 8) * 64;
    #pragma unroll
    for (int i = 0; i < 2; i++) wlb[i] = 16384 + (w * 16 + i * 8) * 64;

    f32x4 acc[2][4];
    #pragma unroll
    for (int im = 0; im < 2; im++)
        #pragma unroll
        for (int in = 0; in < 4; in++) acc[im][in] = (f32x4){0.f, 0.f, 0.f, 0.f};

    // stage tile 0 into buffer 0
    #pragma unroll
    for (int i = 0; i < 4; i++)
        __builtin_amdgcn_global_load_lds((gas_p)agp[i], (las_p)&SM[alb[i]], 16, 0, 0);
    #pragma unroll
    for (int i = 0; i < 2; i++)
        __builtin_amdgcn_global_load_lds((gas_p)wgp[i], (las_p)&SM[wlb[i]], 16, 0, 0);

    int nk = K >> 6;   // K/64
    for (int kt = 0; kt < nk; kt++) {
        __syncthreads();
        int cur = kt & 1, nxt = cur ^ 1;
        if (kt + 1 < nk) {
            int ko = (kt + 1) * 64;
            #pragma unroll
            for (int i = 0; i < 4; i++)
                __builtin_amdgcn_global_load_lds((gas_p)(agp[i] + ko),
                    (las_p)&SM[nxt * 8192 + alb[i]], 16, 0, 0);
            #pragma unroll
            for (int i = 0; i < 2; i++)
                __builtin_amdgcn_global_load_lds((gas_p)(wgp[i] + ko),
                    (las_p)&SM[wlb[i] + nxt * 4096], 16, 0, 0);
        }
        #pragma unroll
        for (int kk = 0; kk < 2; kk++) {
            bf16x8 bf[4];
            #pragma unroll
            for (int in = 0; in < 4; in++)
                bf[in] = *(const bf16x8*)&SM[16384 + cur * 4096 +
                                             (in * 16 + m_) * 64 + kk * 32 + quad * 8];
            #pragma unroll
            for (int im = 0; im < 2; im++) {
                bf16x8 af = *(const bf16x8*)&SM[cur * 8192 +
                                                (w * 32 + im * 16 + m_) * 64 + kk * 32 + quad * 8];
                #pragma unroll
                for (int in = 0; in < 4; in++)
                    acc[im][in] = __builtin_amdgcn_mfma_f32_16x16x32_bf16(af, bf[in], acc[im][in], 0, 0, 0);
            }
        }
    }

    if (MODE == 1) {
        #pragma unroll
        for (int im = 0; im < 2; im++)
            #pragma unroll
            for (int r = 0; r < 4; r++) {
                int row = m0 + w * 32 + im * 16 + quad * 4 + r;
                #pragma unroll
                for (int in = 0; in < 4; in++)
                    Cout[(size_t)row * Dn + (n0 + in * 16 + m_)] = acc[im][in][r];
            }
        return;
    }

    if (region <= 1) {
        // ---- fused LoRA(q) + RMSNorm + partial RoPE + gain(q) ----
        float blc[4][8];
        if (region == 0) {
            #pragma unroll
            for (int in = 0; in < 4; in++) {
                const float* bp = BqL + (size_t)(n0 + in * 16 + m_) * 8;
                #pragma unroll
                for (int j = 0; j < 8; j++) blc[in][j] = bp[j];
            }
        }
        // 0.18033688 = (1/sqrt(64)) * log2(e): fold softmax scale into q so
        // attention computes p = exp2(q.k) with zero per-score multiplies.
        float ghead = (region == 0) ? qgain[n0 >> 6] * 0.18033688011112042f : 1.0f;
        #pragma unroll
        for (int im = 0; im < 2; im++) {
            #pragma unroll
            for (int r = 0; r < 4; r++) {
                int row = m0 + w * 32 + im * 16 + quad * 4 + r;
                float vv[4];
                float ss = 0.f;
                if (region == 0) {
                    const float* tp = g_tq + (size_t)row * 8;
                    float tv8[8];
                    #pragma unroll
                    for (int j = 0; j < 8; j++) tv8[j] = tp[j];
                    #pragma unroll
                    for (int in = 0; in < 4; in++) {
                        float val = acc[im][in][r];
                        #pragma unroll
                        for (int j = 0; j < 8; j++) val += tv8[j] * blc[in][j];
                        vv[in] = val; ss += val * val;
                    }
                } else {
                    #pragma unroll
                    for (int in = 0; in < 4; in++) { vv[in] = acc[im][in][r]; ss += vv[in] * vv[in]; }
                }
                ss += __shfl_xor(ss, 1); ss += __shfl_xor(ss, 2);
                ss += __shfl_xor(ss, 4); ss += __shfl_xor(ss, 8);
                float rs = rsqrtf(ss * (1.0f / 64.0f) + 1.1920929e-7f);
                #pragma unroll
                for (int in = 0; in < 4; in++) vv[in] *= rs;
                float p = __shfl_xor(vv[0], 8);
                int t = row & (Tn - 1);
                float fr = (float)t * exp2f(-(float)(m_ & 7) * 1.6609640474436813f);
                float c = cosf(fr), sn = sinf(fr);
                if (m_ < 16) vv[0] = (m_ < 8) ? vv[0] * c + p * sn : p * sn - vv[0] * c;
                #pragma unroll
                for (int in = 0; in < 4; in++) {
                    float val = vv[in] * ghead;
                    int col = n0 + in * 16 + m_;
                    if (region == 0) g_q[(size_t)row * Dn + col] = f2bf(val);
                    else             g_k[(size_t)row * KDn + (col - 1024)] = f2bf(val);
                }
            }
        }
    } else {
        // ---- region 2: LoRA(v) + LDS transpose -> coalesced g_vt store ----
        float blc[4][8];
        #pragma unroll
        for (int in = 0; in < 4; in++) {
            const float* bp = BvL + (size_t)(n0 - 1280 + in * 16 + m_) * 8;
            #pragma unroll
            for (int j = 0; j < 8; j++) blc[in][j] = bp[j];
        }
        __syncthreads();   // k-loop LDS now dead for all waves
        #pragma unroll
        for (int im = 0; im < 2; im++) {
            #pragma unroll
            for (int r = 0; r < 4; r++) {
                int rl = w * 32 + im * 16 + quad * 4 + r;   // local t
                const float* tp = g_tv + (size_t)(m0 + rl) * 8;
                float tv8[8];
                #pragma unroll
                for (int j = 0; j < 8; j++) tv8[j] = tp[j];
                #pragma unroll
                for (int in = 0; in < 4; in++) {
                    float val = acc[im][in][r];
                    #pragma unroll
                    for (int j = 0; j < 8; j++) val += tv8[j] * blc[in][j];
                    SM[(in * 16 + m_) * 136 + rl] = f2bf(val);  // [d][t], stride 136
                }
            }
        }
        __syncthreads();
        int d = tid >> 2, tseg = (tid & 3) * 32;
        int bb = m0 >> 11, t0 = m0 & (Tn - 1);
        int kvh = (n0 - 1280) >> 6;
        unsigned short* dst = g_vt + (((size_t)(bb * NKVn + kvh) * 64) + d) * Tn + t0 + tseg;
        const uint4* srcv = (const uint4*)&SM[d * 136 + tseg];
        uint4 c0 = srcv[0], c1 = srcv[1], c2 = srcv[2], c3 = srcv[3];
        ((uint4*)dst)[0] = c0; ((uint4*)dst)[1] = c1;
        ((uint4*)dst)[2] = c2; ((uint4*)dst)[3] = c3;
    }
}

// -------- MFMA flash attention, 64-key tiles (round-4 verified, ~48us) ------
// Cooperative coalesced staging + one-tile-ahead register prefetch (rounds
// 5/6 proved direct-global fragment loads are latency-bound: direct-K 2.5x
// worse, direct-V 1.65x worse). Bank-group audit (r10): the 72-short stride
// puts every LDS access at the b128 floor — conflict level is inherent.
//  * single-buffered K/V in LDS (27648 B) -> 4 blocks/CU
//  * bx flip on (kvh>>1)&1: per-CU causal work ~constant
//  * q pre-scaled by 1/sqrt(64)*log2e in GEMM epilogue -> p = exp2(s) direct
//  * P-pack + y-out via v_cvt_pk_bf16_f32
//  * s_setprio(1) around MFMA clusters
__global__ __launch_bounds__(256, 4)
void attn_kernel() {
    __shared__ __align__(16) unsigned short KS[64 * 72];
    __shared__ __align__(16) unsigned short VS[64 * 72];
    __shared__ __align__(16) unsigned short Pt[4][16 * 72];
    int tid = threadIdx.x;
    int w = tid >> 6, lane = tid & 63;
    int q_ = lane & 15, quad = lane >> 4;
    int b = blockIdx.z, kvh = blockIdx.y, h = kvh * 4 + w;
    int bx = blockIdx.x;
    if ((kvh >> 1) & 1) bx = 127 - bx;      // balance work across co-resident blocks
    int qb = bx * 16;
    int qg = qb + q_;

    const unsigned short* qrow =
        g_q + ((size_t)(b * Tn + qg) * NHn + h) * 64 + quad * 8;
    bf16x8 Qf0 = *(const bf16x8*)qrow;
    bf16x8 Qf1 = *(const bf16x8*)(qrow + 32);

    int srow = tid >> 2, sseg = (tid & 3) * 16;
    const unsigned short* kgp =
        g_k + ((size_t)(b * Tn + srow) * NKVn + kvh) * 64 + sseg;
    const unsigned short* vgp =
        g_vt + ((size_t)(b * NKVn + kvh) * 64 + srow) * Tn + sseg;

    f32x4 accO[4];
    #pragma unroll
    for (int i = 0; i < 4; i++) accO[i] = (f32x4){0.f, 0.f, 0.f, 0.f};
    float lsum = 0.f;
    int ntiles = (qb + 79) >> 6;

    {   // stage tile 0
        uint4 ka = *(const uint4*)kgp, kb = *(const uint4*)(kgp + 8);
        uint4 va = *(const uint4*)vgp, vb = *(const uint4*)(vgp + 8);
        *(uint4*)&KS[srow * 72 + sseg] = ka;
        *(uint4*)&KS[srow * 72 + sseg + 8] = kb;
        *(uint4*)&VS[srow * 72 + sseg] = va;
        *(uint4*)&VS[srow * 72 + sseg + 8] = vb;
    }
    __syncthreads();

    for (int kt = 0; kt < ntiles; kt++) {
        bool pre = (kt + 1 < ntiles);
        uint4 kan, kbn, van, vbn;
        if (pre) {   // register prefetch of next tile; lands under the compute
            const unsigned short* kp = kgp + (size_t)(kt + 1) * (64 * NKVn * 64);
            const unsigned short* vp = vgp + (kt + 1) * 64;
            kan = *(const uint4*)kp; kbn = *(const uint4*)(kp + 8);
            van = *(const uint4*)vp; vbn = *(const uint4*)(vp + 8);
        }

        f32x4 s[4];
        __builtin_amdgcn_s_setprio(1);
        #pragma unroll
        for (int ss = 0; ss < 4; ss++) {
            bf16x8 ka = *(const bf16x8*)&KS[(ss * 16 + q_) * 72 + quad * 8];
            bf16x8 kb = *(const bf16x8*)&KS[(ss * 16 + q_) * 72 + 32 + quad * 8];
            s[ss] = (f32x4){0.f, 0.f, 0.f, 0.f};
            s[ss] = __builtin_amdgcn_mfma_f32_16x16x32_bf16(ka, Qf0, s[ss], 0, 0, 0);
            s[ss] = __builtin_amdgcn_mfma_f32_16x16x32_bf16(kb, Qf1, s[ss], 0, 0, 0);
        }
        __builtin_amdgcn_s_setprio(0);

        if (kt == ntiles - 1) {
            #pragma unroll
            for (int ss = 0; ss < 4; ss++) {
                int k0 = kt * 64 + ss * 16 + quad * 4;
                #pragma unroll
                for (int r = 0; r < 4; r++)
                    if (k0 + r > qg) s[ss][r] = -1e30f;
            }
        }
        float p[4][4];
        #pragma unroll
        for (int ss = 0; ss < 4; ss++)
            #pragma unroll
            for (int r = 0; r < 4; r++) {
                p[ss][r] = exp2f(s[ss][r]);   // scale pre-folded into q
                lsum += p[ss][r];
            }

        unsigned short* pb = &Pt[w][0];
        #pragma unroll
        for (int ss = 0; ss < 4; ss++)
            *(uint2*)&pb[q_ * 72 + ss * 16 + quad * 4] =
                make_uint2(cvtpk(p[ss][0], p[ss][1]), cvtpk(p[ss][2], p[ss][3]));
        bf16x8 pf0 = *(const bf16x8*)&pb[q_ * 72 + quad * 8];
        bf16x8 pf1 = *(const bf16x8*)&pb[q_ * 72 + 32 + quad * 8];

        __builtin_amdgcn_s_setprio(1);
        #pragma unroll
        for (int c = 0; c < 4; c++) {
            bf16x8 vf0 = *(const bf16x8*)&VS[(c * 16 + q_) * 72 + quad * 8];
            bf16x8 vf1 = *(const bf16x8*)&VS[(c * 16 + q_) * 72 + 32 + quad * 8];
            accO[c] = __builtin_amdgcn_mfma_f32_16x16x32_bf16(vf0, pf0, accO[c], 0, 0, 0);
            accO[c] = __builtin_amdgcn_mfma_f32_16x16x32_bf16(vf1, pf1, accO[c], 0, 0, 0);
        }
        __builtin_amdgcn_s_setprio(0);

        __syncthreads();               // all reads of KS/VS for this tile done
        if (pre) {
            *(uint4*)&KS[srow * 72 + sseg] = kan;
            *(uint4*)&KS[srow * 72 + sseg + 8] = kbn;
            *(uint4*)&VS[srow * 72 + sseg] = van;
            *(uint4*)&VS[srow * 72 + sseg + 8] = vbn;
        }
        __syncthreads();               // next tile staged
    }

    lsum += __shfl_xor(lsum, 16);
    lsum += __shfl_xor(lsum, 32);
    float invl = 1.0f / lsum;
    unsigned short* yp = g_y + ((size_t)(b * Tn + qg) * NHn + h) * 64;
    #pragma unroll
    for (int c = 0; c < 4; c++) {
        uint2 o = make_uint2(cvtpk(accO[c][0] * invl, accO[c][1] * invl),
                             cvtpk(accO[c][2] * invl, accO[c][3] * invl));
        *(uint2*)&yp[c * 16 + quad * 4] = o;
    }
}

// ----------------------------------------------------------------------------
extern "C" void kernel_launch(void* const* d_in, const int* in_sizes, int n_in,
                              void* d_out, int out_size, void* d_ws, size_t ws_size,
                              hipStream_t stream) {
    const float* x  = (const float*)d_in[0];
    const float* Wq = (const float*)d_in[1];
    const float* Wk = (const float*)d_in[2];
    const float* Wv = (const float*)d_in[3];
    const float* Wp = (const float*)d_in[4];
    const float* qg = (const float*)d_in[5];
    const float* Aq = (const float*)d_in[6];
    const float* Bq = (const float*)d_in[7];
    const float* Av = (const float*)d_in[8];
    const float* Bv = (const float*)d_in[9];
    float* out = (float*)d_out;

    prep<<<dim3(CASTB + Rn / 4), dim3(256), 0, stream>>>(x, Aq, Av, Wq, Wk, Wv, Wp);
    gemm_bt<0><<<dim3(1536 / 64, Rn / 128), dim3(256), 0, stream>>>(
        nullptr, Bq, Bv, qg, Rn, Dn);
    attn_kernel<<<dim3(Tn / 16, NKVn, 2), dim3(256), 0, stream>>>();
    gemm_bt<1><<<dim3(Dn / 64, Rn / 128), dim3(256), 0, stream>>>(
        out, nullptr, nullptr, nullptr, Rn, Dn);
}

// Round 15
// 186.158 us; speedup vs baseline: 1.1416x; 1.0050x over previous
//
#include <hip/hip_runtime.h>

#define Tn   2048
#define Dn   1024
#define KDn  256
#define NHn  16
#define NKVn 4
#define Rn   4096   // B*T

typedef short bf16x8 __attribute__((ext_vector_type(8)));
typedef float f32x4  __attribute__((ext_vector_type(4)));
typedef const __attribute__((address_space(1))) unsigned* gas_p;
typedef __attribute__((address_space(3))) unsigned* las_p;

// ---- device-global intermediates; referenced ONLY from device code ---------
__device__ unsigned short g_q[(size_t)Rn * Dn];              // [b][t][h][d]
__device__ unsigned short g_k[(size_t)Rn * KDn];             // [b][t][kvh][d]
__device__ unsigned short g_vt[(size_t)2 * NKVn * 64 * Tn];  // [b][kvh][d][t]
__device__ unsigned short g_y[(size_t)Rn * Dn];              // [b][t][h][d]
__device__ unsigned short g_xb[(size_t)Rn * Dn];             // bf16 x
__device__ unsigned short g_wq[(size_t)Dn * Dn];
__device__ unsigned short g_wk[(size_t)KDn * Dn];
__device__ unsigned short g_wv[(size_t)KDn * Dn];
__device__ unsigned short g_wp[(size_t)Dn * Dn];
__device__ float g_tq[Rn * 8];
__device__ float g_tv[Rn * 8];

static __device__ __forceinline__ float bf2f(unsigned short u) {
    return __uint_as_float(((unsigned)u) << 16);
}
static __device__ __forceinline__ unsigned short f2bf(float f) {
    unsigned u = __float_as_uint(f);
    u += 0x7fffu + ((u >> 16) & 1u);   // round-to-nearest-even
    return (unsigned short)(u >> 16);
}
static __device__ __forceinline__ unsigned pk2bf(float a, float b) {
    return (unsigned)f2bf(a) | ((unsigned)f2bf(b) << 16);
}
// single-instruction packed bf16 convert (RNE), attn-internal use
static __device__ __forceinline__ unsigned cvtpk(float a, float b) {
    unsigned r;
    asm("v_cvt_pk_bf16_f32 %0, %1, %2" : "=v"(r) : "v"(a), "v"(b));
    return r;
}
static __device__ __forceinline__ float wave_sum(float s) {
    #pragma unroll
    for (int off = 32; off; off >>= 1) s += __shfl_xor(s, off);
    return s;
}

// ---- fused prep: weight cast (blocks 0..2559) + LoRA temporaries -----------
// cast_w and lora_tmp merged into one launch (verified round 10).
#define NQ4 (Dn * Dn / 4)
#define NK4 (KDn * Dn / 4)
#define CASTB ((NQ4 * 2 + NK4 * 2) / 256)   // 2560 blocks of cast work
__global__ __launch_bounds__(256)
void prep(const float* __restrict__ x,
          const float* __restrict__ Aq,
          const float* __restrict__ Av,
          const float* __restrict__ Wq, const float* __restrict__ Wk,
          const float* __restrict__ Wv, const float* __restrict__ Wp) {
    if (blockIdx.x < CASTB) {
        // ---- weight cast Wq|Wk|Wv|Wp -> bf16 ----
        int i = blockIdx.x * 256 + threadIdx.x;
        const float* src; unsigned short* dst; int o;
        if      (i < NQ4)                 { src = Wq; dst = g_wq; o = i; }
        else if (i < NQ4 + NK4)           { src = Wk; dst = g_wk; o = i - NQ4; }
        else if (i < NQ4 + 2 * NK4)       { src = Wv; dst = g_wv; o = i - NQ4 - NK4; }
        else                              { src = Wp; dst = g_wp; o = i - NQ4 - 2 * NK4; }
        float4 v = ((const float4*)src)[o];
        ((uint2*)dst)[o] = make_uint2(pk2bf(v.x, v.y), pk2bf(v.z, v.w));
        return;
    }
    // ---- LoRA temporaries tq/tv = x@A^T + fused x fp32->bf16 cast ----
    int tid = threadIdx.x, wave = tid >> 6, lane = tid & 63;
    int row = (blockIdx.x - CASTB) * 4 + wave;
    const float4* xr = (const float4*)(x + (size_t)row * Dn);
    uint2* xbo = (uint2*)g_xb + (size_t)row * (Dn / 4);
    float aq[8], av[8];
    #pragma unroll
    for (int r = 0; r < 8; r++) { aq[r] = 0.f; av[r] = 0.f; }
    for (int it = 0; it < Dn / 256; it++) {
        int j = it * 64 + lane;
        float4 xv = xr[j];
        xbo[j] = make_uint2(pk2bf(xv.x, xv.y), pk2bf(xv.z, xv.w));
        #pragma unroll
        for (int r = 0; r < 8; r++) {
            float4 a4 = ((const float4*)(Aq + (size_t)r * Dn))[j];
            aq[r] += xv.x * a4.x + xv.y * a4.y + xv.z * a4.z + xv.w * a4.w;
        }
        #pragma unroll
        for (int r = 0; r < 8; r++) {
            float4 a4 = ((const float4*)(Av + (size_t)r * Dn))[j];
            av[r] += xv.x * a4.x + xv.y * a4.y + xv.z * a4.z + xv.w * a4.w;
        }
    }
    #pragma unroll
    for (int r = 0; r < 8; r++) { aq[r] = wave_sum(aq[r]); av[r] = wave_sum(av[r]); }
    if (lane == 0) {
        #pragma unroll
        for (int r = 0; r < 8; r++) { g_tq[row * 8 + r] = aq[r]; g_tv[row * 8 + r] = av[r]; }
    }
}

// ---- MFMA GEMM, 128x64 tile, BK=64, gll double-buffer ----------------------
// VERIFIED OPTIMUM (rounds 10/13, 187-190us end-to-end). 128x64 beats 128^2
// for these skinny GEMMs (3/2 blocks per CU vs 1.5/1 — r11/r12 A/B); BK=64
// (r1->r2 -25us); bijective chunked XCD swizzle; counted-vmcnt neutral (r9).
// MODE 0 = fused QKV over concatenated N=1536:
//   region 0 (cols 0..1023):    Wq -> +LoRA -> RMSNorm+RoPE+gain -> g_q
//     (gain pre-multiplied by 0.125*log2e so attn uses exp2(s) directly)
//   region 1 (cols 1024..1279): Wk ->          RMSNorm+RoPE       -> g_k
//   region 2 (cols 1280..1535): Wv -> +LoRA -> LDS transpose -> g_vt coalesced
// MODE 1 = out: A=g_y, W=g_wp, C=Cout fp32.
template<int MODE>
__global__ __launch_bounds__(256, 2)
void gemm_bt(float* __restrict__ Cout, const float* __restrict__ BqL,
             const float* __restrict__ BvL, const float* __restrict__ qgain,
             int M, int K) {
    const unsigned short* A = (MODE == 0) ? g_xb : g_y;

    // ---- chunked XCD swizzle (bijective: gridDim.x*gridDim.y % 8 == 0) ----
    int gx = gridDim.x;
    int flat = blockIdx.y * gx + blockIdx.x;
    int cpx = (gx * gridDim.y) >> 3;
    int flat2 = (flat & 7) * cpx + (flat >> 3);
    int n0 = (flat2 % gx) * 64, m0 = (flat2 / gx) * 128;

    const unsigned short* W;
    int wroff, region;
    if (MODE == 0) {
        if (n0 < 1024)      { W = g_wq; wroff = n0;        region = 0; }
        else if (n0 < 1280) { W = g_wk; wroff = n0 - 1024; region = 1; }
        else                { W = g_wv; wroff = n0 - 1280; region = 2; }
    } else { W = g_wp; wroff = n0; region = 3; }

    // SM (shorts): [0..16383]      = As double buffer (2 x 128 x 64)
    //              [16384..24575]  = Ws double buffer (2 x 64 x 64)
    // region-2 epilogue reuses SM[0..8703] as 64 x (stride 136) transpose buf
    __shared__ __align__(16) unsigned short SM[24576];
    int tid = threadIdx.x;
    int w = tid >> 6, lane = tid & 63;
    int m_ = lane & 15, quad = lane >> 4;

    // gll lane mapping at BK=64 (128B rows, 8 rows per 1KB wave-instruction)
    int lrow = lane >> 3, lseg = (lane & 7) * 8;
    const unsigned short* agp[4];
    #pragma unroll
    for (int i = 0; i < 4; i++)
        agp[i] = A + (size_t)(m0 + w * 32 + i * 8 + lrow) * K + lseg;
    const unsigned short* wgp[2];
    #pragma unroll
    for (int i = 0; i < 2; i++)
        wgp[i] = W + (size_t)(wroff + w * 16 + i * 8 + lrow) * K + lseg;
    int alb[4], wlb[2];
    #pragma unroll
    for (int i = 0; i < 4; i++) alb[i] = (w * 32 + i * 8) * 64;
    #pragma unroll
    for (int i = 0; i < 2; i++) wlb[i] = 16384 + (w * 16 + i * 8) * 64;

    f32x4 acc[2][4];
    #pragma unroll
    for (int im = 0; im < 2; im++)
        #pragma unroll
        for (int in = 0; in < 4; in++) acc[im][in] = (f32x4){0.f, 0.f, 0.f, 0.f};

    // stage tile 0 into buffer 0
    #pragma unroll
    for (int i = 0; i < 4; i++)
        __builtin_amdgcn_global_load_lds((gas_p)agp[i], (las_p)&SM[alb[i]], 16, 0, 0);
    #pragma unroll
    for (int i = 0; i < 2; i++)
        __builtin_amdgcn_global_load_lds((gas_p)wgp[i], (las_p)&SM[wlb[i]], 16, 0, 0);

    int nk = K >> 6;   // K/64
    for (int kt = 0; kt < nk; kt++) {
        __syncthreads();
        int cur = kt & 1, nxt = cur ^ 1;
        if (kt + 1 < nk) {
            int ko = (kt + 1) * 64;
            #pragma unroll
            for (int i = 0; i < 4; i++)
                __builtin_amdgcn_global_load_lds((gas_p)(agp[i] + ko),
                    (las_p)&SM[nxt * 8192 + alb[i]], 16, 0, 0);
            #pragma unroll
            for (int i = 0; i < 2; i++)
                __builtin_amdgcn_global_load_lds((gas_p)(wgp[i] + ko),
                    (las_p)&SM[wlb[i] + nxt * 4096], 16, 0, 0);
        }
        #pragma unroll
        for (int kk = 0; kk < 2; kk++) {
            bf16x8 bf[4];
            #pragma unroll
            for (int in = 0; in < 4; in++)
                bf[in] = *(const bf16x8*)&SM[16384 + cur * 4096 +
                                             (in * 16 + m_) * 64 + kk * 32 + quad * 8];
            #pragma unroll
            for (int im = 0; im < 2; im++) {
                bf16x8 af = *(const bf16x8*)&SM[cur * 8192 +
                                                (w * 32 + im * 16 + m_) * 64 + kk * 32 + quad * 8];
                #pragma unroll
                for (int in = 0; in < 4; in++)
                    acc[im][in] = __builtin_amdgcn_mfma_f32_16x16x32_bf16(af, bf[in], acc[im][in], 0, 0, 0);
            }
        }
    }

    if (MODE == 1) {
        #pragma unroll
        for (int im = 0; im < 2; im++)
            #pragma unroll
            for (int r = 0; r < 4; r++) {
                int row = m0 + w * 32 + im * 16 + quad * 4 + r;
                #pragma unroll
                for (int in = 0; in < 4; in++)
                    Cout[(size_t)row * Dn + (n0 + in * 16 + m_)] = acc[im][in][r];
            }
        return;
    }

    if (region <= 1) {
        // ---- fused LoRA(q) + RMSNorm + partial RoPE + gain(q) ----
        float blc[4][8];
        if (region == 0) {
            #pragma unroll
            for (int in = 0; in < 4; in++) {
                const float* bp = BqL + (size_t)(n0 + in * 16 + m_) * 8;
                #pragma unroll
                for (int j = 0; j < 8; j++) blc[in][j] = bp[j];
            }
        }
        // 0.18033688 = (1/sqrt(64)) * log2(e): fold softmax scale into q so
        // attention computes p = exp2(q.k) with zero per-score multiplies.
        float ghead = (region == 0) ? qgain[n0 >> 6] * 0.18033688011112042f : 1.0f;
        #pragma unroll
        for (int im = 0; im < 2; im++) {
            #pragma unroll
            for (int r = 0; r < 4; r++) {
                int row = m0 + w * 32 + im * 16 + quad * 4 + r;
                float vv[4];
                float ss = 0.f;
                if (region == 0) {
                    const float* tp = g_tq + (size_t)row * 8;
                    float tv8[8];
                    #pragma unroll
                    for (int j = 0; j < 8; j++) tv8[j] = tp[j];
                    #pragma unroll
                    for (int in = 0; in < 4; in++) {
                        float val = acc[im][in][r];
                        #pragma unroll
                        for (int j = 0; j < 8; j++) val += tv8[j] * blc[in][j];
                        vv[in] = val; ss += val * val;
                    }
                } else {
                    #pragma unroll
                    for (int in = 0; in < 4; in++) { vv[in] = acc[im][in][r]; ss += vv[in] * vv[in]; }
                }
                ss += __shfl_xor(ss, 1); ss += __shfl_xor(ss, 2);
                ss += __shfl_xor(ss, 4); ss += __shfl_xor(ss, 8);
                float rs = rsqrtf(ss * (1.0f / 64.0f) + 1.1920929e-7f);
                #pragma unroll
                for (int in = 0; in < 4; in++) vv[in] *= rs;
                float p = __shfl_xor(vv[0], 8);
                int t = row & (Tn - 1);
                float fr = (float)t * exp2f(-(float)(m_ & 7) * 1.6609640474436813f);
                float c = cosf(fr), sn = sinf(fr);
                if (m_ < 16) vv[0] = (m_ < 8) ? vv[0] * c + p * sn : p * sn - vv[0] * c;
                #pragma unroll
                for (int in = 0; in < 4; in++) {
                    float val = vv[in] * ghead;
                    int col = n0 + in * 16 + m_;
                    if (region == 0) g_q[(size_t)row * Dn + col] = f2bf(val);
                    else             g_k[(size_t)row * KDn + (col - 1024)] = f2bf(val);
                }
            }
        }
    } else {
        // ---- region 2: LoRA(v) + LDS transpose -> coalesced g_vt store ----
        float blc[4][8];
        #pragma unroll
        for (int in = 0; in < 4; in++) {
            const float* bp = BvL + (size_t)(n0 - 1280 + in * 16 + m_) * 8;
            #pragma unroll
            for (int j = 0; j < 8; j++) blc[in][j] = bp[j];
        }
        __syncthreads();   // k-loop LDS now dead for all waves
        #pragma unroll
        for (int im = 0; im < 2; im++) {
            #pragma unroll
            for (int r = 0; r < 4; r++) {
                int rl = w * 32 + im * 16 + quad * 4 + r;   // local t
                const float* tp = g_tv + (size_t)(m0 + rl) * 8;
                float tv8[8];
                #pragma unroll
                for (int j = 0; j < 8; j++) tv8[j] = tp[j];
                #pragma unroll
                for (int in = 0; in < 4; in++) {
                    float val = acc[im][in][r];
                    #pragma unroll
                    for (int j = 0; j < 8; j++) val += tv8[j] * blc[in][j];
                    SM[(in * 16 + m_) * 136 + rl] = f2bf(val);  // [d][t], stride 136
                }
            }
        }
        __syncthreads();
        int d = tid >> 2, tseg = (tid & 3) * 32;
        int bb = m0 >> 11, t0 = m0 & (Tn - 1);
        int kvh = (n0 - 1280) >> 6;
        unsigned short* dst = g_vt + (((size_t)(bb * NKVn + kvh) * 64) + d) * Tn + t0 + tseg;
        const uint4* srcv = (const uint4*)&SM[d * 136 + tseg];
        uint4 c0 = srcv[0], c1 = srcv[1], c2 = srcv[2], c3 = srcv[3];
        ((uint4*)dst)[0] = c0; ((uint4*)dst)[1] = c1;
        ((uint4*)dst)[2] = c2; ((uint4*)dst)[3] = c3;
    }
}

// -------- MFMA flash attention, 64-key tiles (round-4 verified, ~48us) ------
// FINAL: cooperative coalesced staging + one-tile-ahead register prefetch.
// Session A/B ledger for this kernel: direct-K loads 2.5x worse (r5),
// direct-V 1.65x worse (r6), q-pairing +2.3us (r2), key-parity split NaN
// twice with unidentified root cause (r3/r14 — structure retired), LDS
// layout at b128 bank floor (r10 audit), T4 vmcnt neutral (r9).
//  * single-buffered K/V in LDS (27648 B) -> 4 blocks/CU
//  * bx flip on (kvh>>1)&1: per-CU causal work ~constant
//  * q pre-scaled by 1/sqrt(64)*log2e in GEMM epilogue -> p = exp2(s) direct
//  * P-pack + y-out via v_cvt_pk_bf16_f32
//  * s_setprio(1) around MFMA clusters
__global__ __launch_bounds__(256, 4)
void attn_kernel() {
    __shared__ __align__(16) unsigned short KS[64 * 72];
    __shared__ __align__(16) unsigned short VS[64 * 72];
    __shared__ __align__(16) unsigned short Pt[4][16 * 72];
    int tid = threadIdx.x;
    int w = tid >> 6, lane = tid & 63;
    int q_ = lane & 15, quad = lane >> 4;
    int b = blockIdx.z, kvh = blockIdx.y, h = kvh * 4 + w;
    int bx = blockIdx.x;
    if ((kvh >> 1) & 1) bx = 127 - bx;      // balance work across co-resident blocks
    int qb = bx * 16;
    int qg = qb + q_;

    const unsigned short* qrow =
        g_q + ((size_t)(b * Tn + qg) * NHn + h) * 64 + quad * 8;
    bf16x8 Qf0 = *(const bf16x8*)qrow;
    bf16x8 Qf1 = *(const bf16x8*)(qrow + 32);

    int srow = tid >> 2, sseg = (tid & 3) * 16;
    const unsigned short* kgp =
        g_k + ((size_t)(b * Tn + srow) * NKVn + kvh) * 64 + sseg;
    const unsigned short* vgp =
        g_vt + ((size_t)(b * NKVn + kvh) * 64 + srow) * Tn + sseg;

    f32x4 accO[4];
    #pragma unroll
    for (int i = 0; i < 4; i++) accO[i] = (f32x4){0.f, 0.f, 0.f, 0.f};
    float lsum = 0.f;
    int ntiles = (qb + 79) >> 6;

    {   // stage tile 0
        uint4 ka = *(const uint4*)kgp, kb = *(const uint4*)(kgp + 8);
        uint4 va = *(const uint4*)vgp, vb = *(const uint4*)(vgp + 8);
        *(uint4*)&KS[srow * 72 + sseg] = ka;
        *(uint4*)&KS[srow * 72 + sseg + 8] = kb;
        *(uint4*)&VS[srow * 72 + sseg] = va;
        *(uint4*)&VS[srow * 72 + sseg + 8] = vb;
    }
    __syncthreads();

    for (int kt = 0; kt < ntiles; kt++) {
        bool pre = (kt + 1 < ntiles);
        uint4 kan, kbn, van, vbn;
        if (pre) {   // register prefetch of next tile; lands under the compute
            const unsigned short* kp = kgp + (size_t)(kt + 1) * (64 * NKVn * 64);
            const unsigned short* vp = vgp + (kt + 1) * 64;
            kan = *(const uint4*)kp; kbn = *(const uint4*)(kp + 8);
            van = *(const uint4*)vp; vbn = *(const uint4*)(vp + 8);
        }

        f32x4 s[4];
        __builtin_amdgcn_s_setprio(1);
        #pragma unroll
        for (int ss = 0; ss < 4; ss++) {
            bf16x8 ka = *(const bf16x8*)&KS[(ss * 16 + q_) * 72 + quad * 8];
            bf16x8 kb = *(const bf16x8*)&KS[(ss * 16 + q_) * 72 + 32 + quad * 8];
            s[ss] = (f32x4){0.f, 0.f, 0.f, 0.f};
            s[ss] = __builtin_amdgcn_mfma_f32_16x16x32_bf16(ka, Qf0, s[ss], 0, 0, 0);
            s[ss] = __builtin_amdgcn_mfma_f32_16x16x32_bf16(kb, Qf1, s[ss], 0, 0, 0);
        }
        __builtin_amdgcn_s_setprio(0);

        if (kt == ntiles - 1) {
            #pragma unroll
            for (int ss = 0; ss < 4; ss++) {
                int k0 = kt * 64 + ss * 16 + quad * 4;
                #pragma unroll
                for (int r = 0; r < 4; r++)
                    if (k0 + r > qg) s[ss][r] = -1e30f;
            }
        }
        float p[4][4];
        #pragma unroll
        for (int ss = 0; ss < 4; ss++)
            #pragma unroll
            for (int r = 0; r < 4; r++) {
                p[ss][r] = exp2f(s[ss][r]);   // scale pre-folded into q
                lsum += p[ss][r];
            }

        unsigned short* pb = &Pt[w][0];
        #pragma unroll
        for (int ss = 0; ss < 4; ss++)
            *(uint2*)&pb[q_ * 72 + ss * 16 + quad * 4] =
                make_uint2(cvtpk(p[ss][0], p[ss][1]), cvtpk(p[ss][2], p[ss][3]));
        bf16x8 pf0 = *(const bf16x8*)&pb[q_ * 72 + quad * 8];
        bf16x8 pf1 = *(const bf16x8*)&pb[q_ * 72 + 32 + quad * 8];

        __builtin_amdgcn_s_setprio(1);
        #pragma unroll
        for (int c = 0; c < 4; c++) {
            bf16x8 vf0 = *(const bf16x8*)&VS[(c * 16 + q_) * 72 + quad * 8];
            bf16x8 vf1 = *(const bf16x8*)&VS[(c * 16 + q_) * 72 + 32 + quad * 8];
            accO[c] = __builtin_amdgcn_mfma_f32_16x16x32_bf16(vf0, pf0, accO[c], 0, 0, 0);
            accO[c] = __builtin_amdgcn_mfma_f32_16x16x32_bf16(vf1, pf1, accO[c], 0, 0, 0);
        }
        __builtin_amdgcn_s_setprio(0);

        __syncthreads();               // all reads of KS/VS for this tile done
        if (pre) {
            *(uint4*)&KS[srow * 72 + sseg] = kan;
            *(uint4*)&KS[srow * 72 + sseg + 8] = kbn;
            *(uint4*)&VS[srow * 72 + sseg] = van;
            *(uint4*)&VS[srow * 72 + sseg + 8] = vbn;
        }
        __syncthreads();               // next tile staged
    }

    lsum += __shfl_xor(lsum, 16);
    lsum += __shfl_xor(lsum, 32);
    float invl = 1.0f / lsum;
    unsigned short* yp = g_y + ((size_t)(b * Tn + qg) * NHn + h) * 64;
    #pragma unroll
    for (int c = 0; c < 4; c++) {
        uint2 o = make_uint2(cvtpk(accO[c][0] * invl, accO[c][1] * invl),
                             cvtpk(accO[c][2] * invl, accO[c][3] * invl));
        *(uint2*)&yp[c * 16 + quad * 4] = o;
    }
}

// ----------------------------------------------------------------------------
extern "C" void kernel_launch(void* const* d_in, const int* in_sizes, int n_in,
                              void* d_out, int out_size, void* d_ws, size_t ws_size,
                              hipStream_t stream) {
    const float* x  = (const float*)d_in[0];
    const float* Wq = (const float*)d_in[1];
    const float* Wk = (const float*)d_in[2];
    const float* Wv = (const float*)d_in[3];
    const float* Wp = (const float*)d_in[4];
    const float* qg = (const float*)d_in[5];
    const float* Aq = (const float*)d_in[6];
    const float* Bq = (const float*)d_in[7];
    const float* Av = (const float*)d_in[8];
    const float* Bv = (const float*)d_in[9];
    float* out = (float*)d_out;

    prep<<<dim3(CASTB + Rn / 4), dim3(256), 0, stream>>>(x, Aq, Av, Wq, Wk, Wv, Wp);
    gemm_bt<0><<<dim3(1536 / 64, Rn / 128), dim3(256), 0, stream>>>(
        nullptr, Bq, Bv, qg, Rn, Dn);
    attn_kernel<<<dim3(Tn / 16, NKVn, 2), dim3(256), 0, stream>>>();
    gemm_bt<1><<<dim3(Dn / 64, Rn / 128), dim3(256), 0, stream>>>(
        out, nullptr, nullptr, nullptr, Rn, Dn);
}